// Round 1
// baseline (1471.773 us; speedup 1.0000x reference)
//
#include <hip/hip_runtime.h>
#include <hip/hip_bf16.h>
#include <stdint.h>

// DecoderScannedRNN: T=256, B=64, D=1024. GRU scan with done-resets.
// Segment-depth decomposition: row (t,b) has depth s = distance to most recent
// reset. Phase s = gathered GEMM over the h-half (K=1024) x [3D gates], bf16
// MFMA internals, fused GRU epilogue. Stream order gives phase ordering.
// NEW vs previous version:
//  (a) x-projection (ins @ W_i, scan-independent) hoisted out of all phases
//      into one parallel 16384x3072x1024 GEMM (k_xproj) writing bf16 Xp;
//      phase kernels do only the h-half (K halves), epilogue adds xr/xz/xn.
//      Gated on ws_size >= ~108 MB; falls back to proven fused path otherwise.
//  (b) f32->bf16 staging via v_cvt_pk_bf16_f32 (__float22bfloat162_rn) instead
//      of the 5-op manual rounding (staging was VALU/conversion-bound).

#define T_STEPS 256
#define NB 64
#define DIM 1024
#define NPH 32

typedef unsigned short u16;
typedef __attribute__((ext_vector_type(8))) short bf16x8;
typedef __attribute__((ext_vector_type(4))) float f32x4;

__device__ __forceinline__ float b2f(u16 u){ union{unsigned i; float f;} v; v.i=((unsigned)u)<<16; return v.f; }
__device__ __forceinline__ u16 f2b(float f){
  union { __hip_bfloat16 h; u16 u; } v; v.h = __float2bfloat16(f); return v.u;
}
__device__ __forceinline__ unsigned pk2(float lo, float hi){
  union { __hip_bfloat162 h; unsigned u; } v;
  v.h = __float22bfloat162_rn(make_float2(lo, hi));
  return v.u;
}
__device__ __forceinline__ float sigf(float x){ return 1.0f/(1.0f+__expf(-x)); }
__device__ __forceinline__ float tanh_f(float x){ float ax=fabsf(x); float e=__expf(-2.0f*ax); float t=(1.0f-e)/(1.0f+e); return copysignf(t,x); }

// Stage 8 elements (16B of bf16) into LDS from base+eoff (f32 or bf16 source).
__device__ __forceinline__ void stage16(const void* base, size_t eoff, int isf, u16* dst){
  if (isf){
    const float* f = (const float*)base + eoff;
    f32x4 a0 = *(const f32x4*)f;
    f32x4 a1 = *(const f32x4*)(f+4);
    uint4 w;
    w.x = pk2(a0[0],a0[1]); w.y = pk2(a0[2],a0[3]);
    w.z = pk2(a1[0],a1[1]); w.w = pk2(a1[2],a1[3]);
    *(uint4*)dst = w;
  } else {
    *(uint4*)dst = *(const uint4*)((const u16*)base + eoff);
  }
}

// dones mode: 0=int32, 3=f32, 2=bf16, 1=bytes.
// dflag[0]=viol-int, dflag[1]=viol-f32, dflag[2]=viol-bf16, dflag[3]=ins-is-f32.
__device__ __forceinline__ int get_mode(const int* d){
  return (!d[0]) ? 0 : ((!d[1]) ? 3 : ((!d[2]) ? 2 : 1));
}
__device__ __forceinline__ int get_done(const void* dn, int mode, int i){
  if (mode == 0) return ((const int*)dn)[i] != 0;
  if (mode == 3) return ((const unsigned*)dn)[i] != 0;
  if (mode == 2) return ((const u16*)dn)[i] != 0;
  return ((const unsigned char*)dn)[i] != 0;
}

__global__ void k_setup0(const void* dones, const void* ins, int* cnt, int* cur, int* dflag){
  int tid = threadIdx.x;
  if (tid < NPH){ cnt[tid]=0; cur[tid]=0; }
  if (tid < 4) dflag[tid]=0;
  __syncthreads();
  const unsigned* di = (const unsigned*)dones;
  int vInt=0, vF32=0, vB16=0;
  for (int i = tid; i < 4096; i += 256){   // 16KB: in-bounds for every dones dtype
    unsigned v = di[i];
    if (v > 1u) vInt = 1;
    if (v != 0u && v != 0x3F800000u) vF32 = 1;
    unsigned h0 = v & 0xFFFFu, h1 = v >> 16;
    if ((h0 != 0u && h0 != 0x3F80u) || (h1 != 0u && h1 != 0x3F80u)) vB16 = 1;
  }
  if (vInt) atomicOr(&dflag[0], 1);
  if (vF32) atomicOr(&dflag[1], 1);
  if (vB16) atomicOr(&dflag[2], 1);
  // ins f32 detect on EVEN u16 halves (little-endian low half = mantissa bits
  // for f32 -> exp-field uniform 0..255; real bf16 N(0,1) values stay <= ~130).
  const u16* iu = (const u16*)ins;
  int f = 0;
  for (int i = tid; i < 4096; i += 256){
    u16 u = iu[2*i];
    if (((u >> 7) & 0xFF) >= 160) f = 1;
  }
  if (f) atomicOr(&dflag[3], 1);
}

__global__ void k_assign(const void* dones, const int* dflag, int* s_of, int* cnt){
  __shared__ unsigned char sd[T_STEPS];
  int b = blockIdx.x, t = threadIdx.x;
  int mode = get_mode(dflag);
  sd[t] = (unsigned char)get_done(dones, mode, t*NB + b);
  __syncthreads();
  int tt = t;
  while (tt > 0 && !sd[tt]) --tt;   // geometric run lengths, avg ~2 iters
  int s = t - tt;
  if (s >= NPH) s = NPH-1;
  s_of[t*NB + b] = s;
  atomicAdd(&cnt[s], 1);
}

__global__ void k_scan(const int* cnt, int* basep, int* cur){
  if (threadIdx.x == 0){
    int a = 0;
    for (int i=0;i<NPH;++i){ basep[i]=a; a += cnt[i]; }
    basep[NPH] = a;
  }
  if (threadIdx.x < NPH) cur[threadIdx.x] = 0;
}

// src code: plain -> ys row; |0x40000000 -> hiddens row; |0x20000000 -> init_carry row
__global__ void k_fill(const void* dones, const int* dflag, const int* s_of,
                       const int* basep, int* cur, int* row_tb, int* row_src){
  int b = blockIdx.x, t = threadIdx.x;
  int mode = get_mode(dflag);
  int s = s_of[t*NB + b];
  int pos = basep[s] + atomicAdd(&cur[s], 1);
  row_tb[pos] = t*NB + b;
  int code;
  if (s > 0) code = (t-1)*NB + b;
  else if (get_done(dones, mode, t*NB + b)) code = (t*NB + b) | 0x40000000;
  else code = b | 0x20000000;
  row_src[pos] = code;
}

// W [1024][3072] -> WT [3072][1024] bf16 (convert if f32).
__global__ void k_transpose(const void* __restrict__ W, u16* __restrict__ WT, const int* dflag){
  __shared__ u16 ts[64][65];
  int k0 = blockIdx.x*64, n0 = blockIdx.y*64, tid = threadIdx.x;
  int isf = dflag[3];
  for (int i = tid; i < 4096; i += 256){
    int r=i>>6, c=i&63; int idx=(k0+r)*3072 + n0 + c;
    ts[r][c] = isf ? f2b(((const float*)W)[idx]) : ((const u16*)W)[idx];
  }
  __syncthreads();
  for (int i = tid; i < 4096; i += 256){
    int r=i>>6, c=i&63;
    WT[(n0+r)*DIM + k0 + c] = ts[c][r];
  }
}

__global__ void k_bias(const void* bi, const void* bhn, const int* dflag,
                       u16* bi_b, u16* bhn_b){
  int isf = dflag[3];
  int i = blockIdx.x*256 + threadIdx.x;      // grid 16 -> 4096
  if (i < 3072) bi_b[i] = isf ? f2b(((const float*)bi)[i]) : ((const u16*)bi)[i];
  else { int j=i-3072; bhn_b[j] = isf ? f2b(((const float*)bhn)[j]) : ((const u16*)bhn)[j]; }
}

// Resolve h-source (ys / hiddens / init_carry) for a row code.
__device__ __forceinline__ void hsrc(int code, const void* outv, const void* hiddens,
                                     const void* initc, const void** hb, size_t* ho){
  if (code & 0x40000000){ *hb = hiddens; *ho = (size_t)(code & 0x0FFFFFFF)*DIM; }
  else if (code & 0x20000000){ *hb = initc; *ho = (size_t)(code & 0x0FFFFFFF)*DIM; }
  else { *hb = outv; *ho = (size_t)NB*DIM + (size_t)code*DIM; }
}

// ---------------------------------------------------------------------------
// Hoisted x-projection GEMM: Xp[16384][3072] (bf16) = cvt(ins @ Wi).
// C = A[16384][1024] x WiT[3072][1024]^T. Tiles 128x128, BK=64, 4 waves (2x2),
// each wave a 64x64 sub-tile. No bias (added in phase epilogue). Fully
// parallel; 3072 blocks = exactly the tile count.
// ---------------------------------------------------------------------------
__global__ __launch_bounds__(256) void k_xproj(
    const void* __restrict__ ins, const u16* __restrict__ WiT,
    const int* __restrict__ dflag, u16* __restrict__ xp)
{
  __shared__ u16 As[128*64];
  __shared__ u16 Bs[128*64];
  int isf = dflag[3];
  int tid=threadIdx.x, wave=tid>>6, lane=tid&63, quad=lane>>4, l16=lane&15;
  int wm=wave&1, wn=wave>>1;
  int srow = wave*8 + (lane>>3), c8=(lane&7)*8;
  int tn = blockIdx.x % 24, tm = blockIdx.x / 24;   // consecutive blocks share A tile
  f32x4 acc[4][4] = {};
  #pragma unroll 1
  for (int ko=0; ko<1024; ko+=64){
    #pragma unroll
    for (int p=0;p<4;++p)
      stage16(ins, (size_t)(tm*128 + p*32 + srow)*DIM + c8 + ko, isf, &As[(p*32+srow)*64+c8]);
    #pragma unroll
    for (int p=0;p<4;++p)
      *(uint4*)&Bs[(p*32+srow)*64+c8] =
          *(const uint4*)(WiT + (size_t)(tn*128 + p*32 + srow)*DIM + c8 + ko);
    __syncthreads();
    #pragma unroll
    for (int kk=0;kk<64;kk+=32){
      bf16x8 af[4], bfv[4];
      #pragma unroll
      for (int mi=0;mi<4;++mi) af[mi]  = *(const bf16x8*)&As[(wm*64+mi*16+l16)*64+kk+quad*8];
      #pragma unroll
      for (int ni=0;ni<4;++ni) bfv[ni] = *(const bf16x8*)&Bs[(wn*64+ni*16+l16)*64+kk+quad*8];
      #pragma unroll
      for (int mi=0;mi<4;++mi)
        #pragma unroll
        for (int ni=0;ni<4;++ni)
          acc[mi][ni] = __builtin_amdgcn_mfma_f32_16x16x32_bf16(af[mi],bfv[ni],acc[mi][ni],0,0,0);
    }
    __syncthreads();
  }
  #pragma unroll
  for (int mi=0;mi<4;++mi){
    int row = tm*128 + wm*64 + mi*16 + quad*4;
    #pragma unroll
    for (int ni=0;ni<4;++ni){
      int colB = tn*128 + wn*64 + ni*16 + l16;
      u16* op = xp + (size_t)row*3072 + colB;
      #pragma unroll
      for (int j=0;j<4;++j)
        op[(size_t)j*3072] = f2b(acc[mi][ni][j]);
    }
  }
}

// ---------------------------------------------------------------------------
// Fat phase: 128 rows x 32 d-cols (96 gate cols).
// HOIST=false: K=2048 in two halves; acc groups 0=r,1=z,2=n_x,3=n_h.
// HOIST=true : K=1024 (h half only); acc groups 0=r,1=z,2=n_h; x from Xp.
// ---------------------------------------------------------------------------
template<bool HOIST>
__global__ __launch_bounds__(256) void phase_fat(
    int s, const int* __restrict__ pcnt, const int* __restrict__ pbase,
    const int* __restrict__ row_tb, const int* __restrict__ row_src,
    const void* __restrict__ ins, const void* __restrict__ hiddens,
    const void* __restrict__ initc, const u16* __restrict__ WiT,
    const u16* __restrict__ WhT, const u16* __restrict__ bi_b,
    const u16* __restrict__ bhn_b, const int* __restrict__ dflag,
    const u16* __restrict__ xp, void* __restrict__ outv)
{
  int count = pcnt[s];
  if (count <= 0) return;
  int isf = dflag[3];
  int base = pbase[s];
  int mtiles = (count + 127) >> 7;
  int ntot = mtiles << 5;
  __shared__ u16 As[128*64];
  __shared__ u16 Bs[96*64];
  int tid=threadIdx.x, wave=tid>>6, lane=tid&63, quad=lane>>4, l16=lane&15;
  int wm=wave&1, wn=wave>>1;
  int srow = wave*8 + (lane>>3), c8=(lane&7)*8;
  constexpr int NG = HOIST ? 3 : 4;

  for (int tile = blockIdx.x; tile < ntot; tile += gridDim.x){
    int tm = tile >> 5, dblk = tile & 31, d0 = dblk*32;
    size_t xoff[4], hoff[4];
    const void* hbv[4];
    #pragma unroll
    for (int p=0;p<4;++p){
      int lr = tm*128 + p*32 + srow;
      int idx = base + ((lr < count) ? lr : 0);
      int tb = row_tb[idx], code = row_src[idx];
      xoff[p] = (size_t)tb*DIM + c8;
      size_t ho; const void* hb;
      hsrc(code, outv, hiddens, initc, &hb, &ho);
      hbv[p] = hb; hoff[p] = ho + c8;
    }
    int boff[3];
    #pragma unroll
    for (int p=0;p<3;++p) boff[p] = (p*DIM + d0 + srow)*DIM + c8;
    f32x4 acc[4][NG] = {};

    if constexpr (!HOIST){
      // ---- x half: A = ins rows, B = WiT, n-gate into group 2 ----
      #pragma unroll 1
      for (int ko=0; ko<1024; ko+=64){
        #pragma unroll
        for (int p=0;p<4;++p) stage16(ins, xoff[p]+ko, isf, &As[(p*32+srow)*64+c8]);
        #pragma unroll
        for (int p=0;p<3;++p) *(uint4*)&Bs[(p*32+srow)*64+c8] = *(const uint4*)(WiT + boff[p] + ko);
        __syncthreads();
        #pragma unroll
        for (int kk=0;kk<64;kk+=32){
          bf16x8 af[4];
          #pragma unroll
          for (int mi=0;mi<4;++mi) af[mi] = *(const bf16x8*)&As[(wm*64+mi*16+l16)*64+kk+quad*8];
          #pragma unroll
          for (int g=0;g<3;++g){
            bf16x8 bfr = *(const bf16x8*)&Bs[(g*32 + wn*16 + l16)*64+kk+quad*8];
            #pragma unroll
            for (int mi=0;mi<4;++mi)
              acc[mi][g] = __builtin_amdgcn_mfma_f32_16x16x32_bf16(af[mi],bfr,acc[mi][g],0,0,0);
          }
        }
        __syncthreads();
      }
    }
    // ---- h half: A = h rows, B = WhT, n-gate into group NG-1 ----
    #pragma unroll 1
    for (int ko=0; ko<1024; ko+=64){
      #pragma unroll
      for (int p=0;p<4;++p) stage16(hbv[p], hoff[p]+ko, isf, &As[(p*32+srow)*64+c8]);
      #pragma unroll
      for (int p=0;p<3;++p) *(uint4*)&Bs[(p*32+srow)*64+c8] = *(const uint4*)(WhT + boff[p] + ko);
      __syncthreads();
      #pragma unroll
      for (int kk=0;kk<64;kk+=32){
        bf16x8 af[4];
        #pragma unroll
        for (int mi=0;mi<4;++mi) af[mi] = *(const bf16x8*)&As[(wm*64+mi*16+l16)*64+kk+quad*8];
        #pragma unroll
        for (int g=0;g<3;++g){
          bf16x8 bfr = *(const bf16x8*)&Bs[(g*32 + wn*16 + l16)*64+kk+quad*8];
          int grp = (g==2) ? (NG-1) : g;
          #pragma unroll
          for (int mi=0;mi<4;++mi)
            acc[mi][grp] = __builtin_amdgcn_mfma_f32_16x16x32_bf16(af[mi],bfr,acc[mi][grp],0,0,0);
        }
      }
      __syncthreads();
    }
    // ---- fused GRU epilogue ----
    int col = d0 + wn*16 + l16;
    float br = b2f(bi_b[col]), bz = b2f(bi_b[1024+col]);
    float bn = b2f(bi_b[2048+col]), bh = b2f(bhn_b[col]);
    #pragma unroll
    for (int mi=0;mi<4;++mi){
      int lrow0 = tm*128 + wm*64 + mi*16 + quad*4;
      #pragma unroll
      for (int j=0;j<4;++j){
        int lrow = lrow0 + j;
        if (lrow >= count) continue;
        int idx = base + lrow;
        int tb = row_tb[idx], code = row_src[idx];
        size_t ho; const void* hb;
        hsrc(code, outv, hiddens, initc, &hb, &ho);
        float hpv = isf ? ((const float*)hb)[ho + col] : b2f(((const u16*)hb)[ho + col]);
        float xr = 0.f, xz = 0.f, xn = 0.f;
        if constexpr (HOIST){
          const u16* xrow = xp + (size_t)tb*3072 + col;
          xr = b2f(xrow[0]); xz = b2f(xrow[1024]); xn = b2f(xrow[2048]);
        }
        float r = sigf(br + xr + acc[mi][0][j]);
        float z = sigf(bz + xz + acc[mi][1][j]);
        float nx = HOIST ? xn : acc[mi][2][j];
        float n = tanh_f(bn + nx + r*(acc[mi][NG-1][j] + bh));
        float hnew = (1.0f - z)*n + z*hpv;
        size_t yo = (size_t)NB*DIM + (size_t)tb*DIM + col;
        if (isf) ((float*)outv)[yo] = hnew;
        else     ((u16*)outv)[yo] = f2b(hnew);
      }
    }
  }
}

// Thin phase: 64 rows x 16 d-cols (48 gate cols). Same HOIST semantics.
template<bool HOIST>
__global__ __launch_bounds__(256) void phase_thin(
    int s, const int* __restrict__ pcnt, const int* __restrict__ pbase,
    const int* __restrict__ row_tb, const int* __restrict__ row_src,
    const void* __restrict__ ins, const void* __restrict__ hiddens,
    const void* __restrict__ initc, const u16* __restrict__ WiT,
    const u16* __restrict__ WhT, const u16* __restrict__ bi_b,
    const u16* __restrict__ bhn_b, const int* __restrict__ dflag,
    const u16* __restrict__ xp, void* __restrict__ outv)
{
  int count = pcnt[s];
  if (count <= 0) return;
  int isf = dflag[3];
  int base = pbase[s];
  int mtiles = (count + 63) >> 6;
  int ntot = mtiles << 6;
  __shared__ u16 As[64*64];
  __shared__ u16 Bs[48*64];
  int tid=threadIdx.x, wave=tid>>6, lane=tid&63, quad=lane>>4, l16=lane&15;
  int srow = wave*8 + (lane>>3), c8=(lane&7)*8;
  constexpr int NG = HOIST ? 3 : 4;

  for (int tile = blockIdx.x; tile < ntot; tile += gridDim.x){
    int tm = tile >> 6, dblk = tile & 63, d0 = dblk*16;
    size_t xoff[2], hoff[2];
    const void* hbv[2];
    #pragma unroll
    for (int p=0;p<2;++p){
      int lr = tm*64 + p*32 + srow;
      int idx = base + ((lr < count) ? lr : 0);
      int tb = row_tb[idx], code = row_src[idx];
      xoff[p] = (size_t)tb*DIM + c8;
      size_t ho; const void* hb;
      hsrc(code, outv, hiddens, initc, &hb, &ho);
      hbv[p] = hb; hoff[p] = ho + c8;
    }
    int boff0 = ((srow>>4)*DIM + d0 + (srow&15))*DIM + c8;   // gates 0,1
    int boff1 = (2*DIM + d0 + srow)*DIM + c8;                // gate 2 (srow<16)
    f32x4 acc[NG] = {};

#define THIN_HALF(ABASE0, AOFF0, ABASE1, AOFF1, WBASE, NGRP)                 \
    _Pragma("unroll 1")                                                      \
    for (int ko=0; ko<1024; ko+=64){                                         \
      stage16(ABASE0, AOFF0 + ko, isf, &As[srow*64+c8]);                     \
      stage16(ABASE1, AOFF1 + ko, isf, &As[(32+srow)*64+c8]);                \
      *(uint4*)&Bs[srow*64+c8] = *(const uint4*)(WBASE + boff0 + ko);        \
      if (srow < 16)                                                         \
        *(uint4*)&Bs[(32+srow)*64+c8] = *(const uint4*)(WBASE + boff1 + ko); \
      __syncthreads();                                                       \
      _Pragma("unroll")                                                      \
      for (int kk=0;kk<64;kk+=32){                                           \
        bf16x8 af = *(const bf16x8*)&As[(wave*16+l16)*64+kk+quad*8];         \
        _Pragma("unroll")                                                    \
        for (int g=0;g<3;++g){                                               \
          bf16x8 bfr = *(const bf16x8*)&Bs[(g*16+l16)*64+kk+quad*8];         \
          int grp = (g==2) ? (NGRP) : g;                                     \
          acc[grp] = __builtin_amdgcn_mfma_f32_16x16x32_bf16(af,bfr,acc[grp],0,0,0); \
        }                                                                    \
      }                                                                      \
      __syncthreads();                                                       \
    }

    if constexpr (!HOIST){
      THIN_HALF(ins, xoff[0], ins, xoff[1], WiT, 2)
    }
    THIN_HALF(hbv[0], hoff[0], hbv[1], hoff[1], WhT, (HOIST ? 2 : 3))
#undef THIN_HALF

    int col = d0 + l16;
    float br = b2f(bi_b[col]), bz = b2f(bi_b[1024+col]);
    float bn = b2f(bi_b[2048+col]), bh = b2f(bhn_b[col]);
    int lrow0 = tm*64 + wave*16 + quad*4;
    #pragma unroll
    for (int j=0;j<4;++j){
      int lrow = lrow0 + j;
      if (lrow >= count) continue;
      int idx = base + lrow;
      int tb = row_tb[idx], code = row_src[idx];
      size_t ho; const void* hb;
      hsrc(code, outv, hiddens, initc, &hb, &ho);
      float hpv = isf ? ((const float*)hb)[ho + col] : b2f(((const u16*)hb)[ho + col]);
      float xr = 0.f, xz = 0.f, xn = 0.f;
      if constexpr (HOIST){
        const u16* xrow = xp + (size_t)tb*3072 + col;
        xr = b2f(xrow[0]); xz = b2f(xrow[1024]); xn = b2f(xrow[2048]);
      }
      float r = sigf(br + xr + acc[0][j]);
      float z = sigf(bz + xz + acc[1][j]);
      float nx = HOIST ? xn : acc[2][j];
      float n = tanh_f(bn + nx + r*(acc[NG-1][j] + bh));
      float hnew = (1.0f - z)*n + z*hpv;
      size_t yo = (size_t)NB*DIM + (size_t)tb*DIM + col;
      if (isf) ((float*)outv)[yo] = hnew;
      else     ((u16*)outv)[yo] = f2b(hnew);
    }
  }
}

__global__ void k_final(const int* dflag, void* out){
  int isf = dflag[3];
  size_t i = (size_t)(blockIdx.x*256 + threadIdx.x)*4;   // 64 blocks -> 65536
  size_t src = (size_t)NB*DIM + (size_t)(T_STEPS-1)*NB*DIM;
  if (isf){
    float* o = (float*)out;
    *(f32x4*)(o + i) = *(const f32x4*)(o + src + i);
  } else {
    u16* o = (u16*)out;
    *(uint2*)(o + i) = *(const uint2*)(o + src + i);
  }
}

extern "C" void kernel_launch(void* const* d_in, const int* in_sizes, int n_in,
                              void* d_out, int out_size, void* d_ws, size_t ws_size,
                              hipStream_t stream){
  const void* ins = d_in[0];
  const void* hid = d_in[1];
  const void* dn  = d_in[2];
  const void* ini = d_in[3];
  const void* Wi  = d_in[4];
  const void* Wh  = d_in[5];
  const void* bi  = d_in[6];
  const void* bhn = d_in[7];

  char* ws = (char*)d_ws;
  int* dflag  = (int*)(ws + 0);
  int* cnt    = (int*)(ws + 256);
  int* basep  = (int*)(ws + 512);
  int* cur    = (int*)(ws + 1024);
  int* s_of   = (int*)(ws + 4096);          // 64 KB
  int* row_tb = (int*)(ws + 69632);         // 64 KB
  int* row_src= (int*)(ws + 135168);        // 64 KB
  u16* bi_b   = (u16*)(ws + 200704);        // 6 KB
  u16* bhn_b  = (u16*)(ws + 208896);        // 2 KB
  u16* WiT    = (u16*)(ws + 262144);        // 6 MB
  u16* WhT    = (u16*)(ws + 6553600);       // 6 MB (end 12845056)
  u16* xp     = (u16*)(ws + 12845056);      // 96 MB bf16 Xp (if ws allows)

  // Hoisted-x path needs 12845056 + 16384*3072*2 = 113508352 bytes.
  const int hoist = (ws_size >= 113508352ull) ? 1 : 0;

  k_setup0<<<1,256,0,stream>>>(dn, ins, cnt, cur, dflag);
  k_assign<<<NB,T_STEPS,0,stream>>>(dn, dflag, s_of, cnt);
  k_scan<<<1,64,0,stream>>>(cnt, basep, cur);
  k_fill<<<NB,T_STEPS,0,stream>>>(dn, dflag, s_of, basep, cur, row_tb, row_src);
  k_transpose<<<dim3(16,48),256,0,stream>>>(Wi, WiT, dflag);
  k_transpose<<<dim3(16,48),256,0,stream>>>(Wh, WhT, dflag);
  k_bias<<<16,256,0,stream>>>(bi, bhn, dflag, bi_b, bhn_b);

  if (hoist){
    k_xproj<<<3072,256,0,stream>>>(ins, WiT, dflag, xp);
    for (int s=0;s<6;++s)
      phase_fat<true><<<1024,256,0,stream>>>(s, cnt, basep, row_tb, row_src, ins, hid, ini,
                                             WiT, WhT, bi_b, bhn_b, dflag, xp, d_out);
    for (int s=6;s<NPH;++s)
      phase_thin<true><<<128,256,0,stream>>>(s, cnt, basep, row_tb, row_src, ins, hid, ini,
                                             WiT, WhT, bi_b, bhn_b, dflag, xp, d_out);
  } else {
    for (int s=0;s<6;++s)
      phase_fat<false><<<1024,256,0,stream>>>(s, cnt, basep, row_tb, row_src, ins, hid, ini,
                                              WiT, WhT, bi_b, bhn_b, dflag, xp, d_out);
    for (int s=6;s<NPH;++s)
      phase_thin<false><<<128,256,0,stream>>>(s, cnt, basep, row_tb, row_src, ins, hid, ini,
                                              WiT, WhT, bi_b, bhn_b, dflag, xp, d_out);
  }
  k_final<<<64,256,0,stream>>>(dflag, d_out);
}

// Round 2
// 1127.968 us; speedup vs baseline: 1.3048x; 1.3048x over previous
//
#include <hip/hip_runtime.h>
#include <hip/hip_bf16.h>
#include <stdint.h>

// DecoderScannedRNN: T=256, B=64, D=1024. GRU scan with done-resets.
// Segment-depth decomposition + hoisted x-projection (see round 0/1 notes).
// NEW this round:
//  (a) 2-phase register prefetch in all GEMM loops: A-row loads for ko+1 issue
//      after the first barrier and fly under ds_read+MFMA (drained at the 2nd
//      barrier, which is after the overlap window).
//  (b) B (weight) panels staged via __builtin_amdgcn_global_load_lds (16B),
//      with PRE-SWIZZLED global source column (LDS dest stays linear).
//  (c) T2 XOR swizzle (col8 ^= row&7) on As/Bs eliminates the 16-way bank
//      conflict on stride-128B ds_read_b128 fragment reads.
//  (d) k_fill is now a deterministic ballot-prefix scan: phase rows sorted by
//      (t,b) -> gathered A rows / epilogue IO are spatially clustered.

#define T_STEPS 256
#define NB 64
#define DIM 1024
#define NPH 32

typedef unsigned short u16;
typedef __attribute__((ext_vector_type(8))) short bf16x8;
typedef __attribute__((ext_vector_type(4))) float f32x4;

__device__ __forceinline__ float b2f(u16 u){ union{unsigned i; float f;} v; v.i=((unsigned)u)<<16; return v.f; }
__device__ __forceinline__ u16 f2b(float f){
  union { __hip_bfloat16 h; u16 u; } v; v.h = __float2bfloat16(f); return v.u;
}
__device__ __forceinline__ unsigned pk2(float lo, float hi){
  union { __hip_bfloat162 h; unsigned u; } v;
  v.h = __float22bfloat162_rn(make_float2(lo, hi));
  return v.u;
}
__device__ __forceinline__ float sigf(float x){ return 1.0f/(1.0f+__expf(-x)); }
__device__ __forceinline__ float tanh_f(float x){ float ax=fabsf(x); float e=__expf(-2.0f*ax); float t=(1.0f-e)/(1.0f+e); return copysignf(t,x); }

// Async global->LDS 16B: dest = wave-uniform lbase + lane*16B. Fallback copies
// manually to the same per-lane slot.
__device__ __forceinline__ void gl_lds16(const u16* g, u16* lbase, int lane){
#if __has_builtin(__builtin_amdgcn_global_load_lds)
  __builtin_amdgcn_global_load_lds(
      (const __attribute__((address_space(1))) unsigned int*)g,
      (__attribute__((address_space(3))) unsigned int*)lbase, 16, 0, 0);
#else
  *(uint4*)(lbase + lane*8) = *(const uint4*)g;
#endif
}

// dones mode: 0=int32, 3=f32, 2=bf16, 1=bytes.
// dflag[0]=viol-int, dflag[1]=viol-f32, dflag[2]=viol-bf16, dflag[3]=ins-is-f32.
__device__ __forceinline__ int get_mode(const int* d){
  return (!d[0]) ? 0 : ((!d[1]) ? 3 : ((!d[2]) ? 2 : 1));
}
__device__ __forceinline__ int get_done(const void* dn, int mode, int i){
  if (mode == 0) return ((const int*)dn)[i] != 0;
  if (mode == 3) return ((const unsigned*)dn)[i] != 0;
  if (mode == 2) return ((const u16*)dn)[i] != 0;
  return ((const unsigned char*)dn)[i] != 0;
}

__global__ void k_setup0(const void* dones, const void* ins, int* cnt, int* cur, int* dflag){
  int tid = threadIdx.x;
  if (tid < NPH){ cnt[tid]=0; cur[tid]=0; }
  if (tid < 4) dflag[tid]=0;
  __syncthreads();
  const unsigned* di = (const unsigned*)dones;
  int vInt=0, vF32=0, vB16=0;
  for (int i = tid; i < 4096; i += 256){   // 16KB: in-bounds for every dones dtype
    unsigned v = di[i];
    if (v > 1u) vInt = 1;
    if (v != 0u && v != 0x3F800000u) vF32 = 1;
    unsigned h0 = v & 0xFFFFu, h1 = v >> 16;
    if ((h0 != 0u && h0 != 0x3F80u) || (h1 != 0u && h1 != 0x3F80u)) vB16 = 1;
  }
  if (vInt) atomicOr(&dflag[0], 1);
  if (vF32) atomicOr(&dflag[1], 1);
  if (vB16) atomicOr(&dflag[2], 1);
  // ins f32 detect on EVEN u16 halves.
  const u16* iu = (const u16*)ins;
  int f = 0;
  for (int i = tid; i < 4096; i += 256){
    u16 u = iu[2*i];
    if (((u >> 7) & 0xFF) >= 160) f = 1;
  }
  if (f) atomicOr(&dflag[3], 1);
}

__global__ void k_assign(const void* dones, const int* dflag, int* s_of, int* cnt){
  __shared__ unsigned char sd[T_STEPS];
  int b = blockIdx.x, t = threadIdx.x;
  int mode = get_mode(dflag);
  sd[t] = (unsigned char)get_done(dones, mode, t*NB + b);
  __syncthreads();
  int tt = t;
  while (tt > 0 && !sd[tt]) --tt;   // geometric run lengths, avg ~2 iters
  int s = t - tt;
  if (s >= NPH) s = NPH-1;
  s_of[t*NB + b] = s;
  atomicAdd(&cnt[s], 1);
}

__global__ void k_scan(const int* cnt, int* basep, int* cur){
  if (threadIdx.x == 0){
    int a = 0;
    for (int i=0;i<NPH;++i){ basep[i]=a; a += cnt[i]; }
    basep[NPH] = a;
  }
  if (threadIdx.x < NPH) cur[threadIdx.x] = 0;
}

// Deterministic sorted fill: one block per phase s; rows with s_of==s are
// emitted in ascending (t,b) order via ballot prefix-sum. Sorted order makes
// phase-GEMM row gathers spatially clustered (L2/DRAM locality).
__global__ void k_fill(const void* dones, const int* dflag, const int* s_of,
                       const int* basep, int* row_tb, int* row_src){
  int s = blockIdx.x;
  __shared__ int runbase;
  __shared__ int wsum[4];
  int tid = threadIdx.x, lane = tid & 63, wave = tid >> 6;
  int mode = get_mode(dflag);
  if (tid == 0) runbase = basep[s];
  __syncthreads();
  for (int i0 = 0; i0 < T_STEPS*NB; i0 += 256){
    int i = i0 + tid;
    int match = (s_of[i] == s);
    unsigned long long mask = __ballot(match);
    if (lane == 0) wsum[wave] = __popcll(mask);
    __syncthreads();
    int off = runbase;
    for (int w = 0; w < wave; ++w) off += wsum[w];
    int total = wsum[0] + wsum[1] + wsum[2] + wsum[3];
    if (match){
      int pos = off + __popcll(mask & ((1ull << lane) - 1ull));
      row_tb[pos] = i;
      int t = i >> 6, b = i & 63;
      int code;
      if (s > 0) code = (t-1)*NB + b;
      else if (get_done(dones, mode, i)) code = i | 0x40000000;
      else code = b | 0x20000000;
      row_src[pos] = code;
    }
    __syncthreads();
    if (tid == 0) runbase += total;
  }
}

// W [1024][3072] -> WT [3072][1024] bf16 (convert if f32).
__global__ void k_transpose(const void* __restrict__ W, u16* __restrict__ WT, const int* dflag){
  __shared__ u16 ts[64][65];
  int k0 = blockIdx.x*64, n0 = blockIdx.y*64, tid = threadIdx.x;
  int isf = dflag[3];
  for (int i = tid; i < 4096; i += 256){
    int r=i>>6, c=i&63; int idx=(k0+r)*3072 + n0 + c;
    ts[r][c] = isf ? f2b(((const float*)W)[idx]) : ((const u16*)W)[idx];
  }
  __syncthreads();
  for (int i = tid; i < 4096; i += 256){
    int r=i>>6, c=i&63;
    WT[(n0+r)*DIM + k0 + c] = ts[c][r];
  }
}

__global__ void k_bias(const void* bi, const void* bhn, const int* dflag,
                       u16* bi_b, u16* bhn_b){
  int isf = dflag[3];
  int i = blockIdx.x*256 + threadIdx.x;      // grid 16 -> 4096
  if (i < 3072) bi_b[i] = isf ? f2b(((const float*)bi)[i]) : ((const u16*)bi)[i];
  else { int j=i-3072; bhn_b[j] = isf ? f2b(((const float*)bhn)[j]) : ((const u16*)bhn)[j]; }
}

// Resolve h-source (ys / hiddens / init_carry) for a row code.
__device__ __forceinline__ void hsrc(int code, const void* outv, const void* hiddens,
                                     const void* initc, const void** hb, size_t* ho){
  if (code & 0x40000000){ *hb = hiddens; *ho = (size_t)(code & 0x0FFFFFFF)*DIM; }
  else if (code & 0x20000000){ *hb = initc; *ho = (size_t)(code & 0x0FFFFFFF)*DIM; }
  else { *hb = outv; *ho = (size_t)NB*DIM + (size_t)code*DIM; }
}

// ---------------------------------------------------------------------------
// Hoisted x-projection GEMM: Xp[16384][3072] (bf16) = cvt(ins @ Wi).
// 128x128 tiles, BK=64, 2x2 waves, pipelined + swizzled.
// ---------------------------------------------------------------------------
__global__ __launch_bounds__(256, 3) void k_xproj(
    const void* __restrict__ ins, const u16* __restrict__ WiT,
    const int* __restrict__ dflag, u16* __restrict__ xp)
{
  __shared__ u16 As[128*64];
  __shared__ u16 Bs[128*64];
  int isf = dflag[3];
  int tid=threadIdx.x, wave=tid>>6, lane=tid&63, quad=lane>>4, l16=lane&15;
  int wm=wave&1, wn=wave>>1;
  int srow = wave*8 + (lane>>3), c8=(lane&7)*8;
  int swzc = c8 ^ ((srow&7)<<3);
  int rsw = (l16&7)<<3;
  int tn = blockIdx.x % 24, tm = blockIdx.x / 24;   // consecutive blocks share A tile
  f32x4 acc[4][4] = {};
  unsigned aoff[4], boff[4];
  #pragma unroll
  for (int p=0;p<4;++p){
    aoff[p] = (unsigned)(tm*128 + p*32 + srow)*DIM + c8;
    boff[p] = (unsigned)(tn*128 + p*32 + srow)*DIM + swzc;
  }
  f32x4 pr0[4], pr1[4];
  #pragma unroll
  for (int p=0;p<4;++p){
    if (isf){ const float* f=(const float*)ins + aoff[p]; pr0[p]=*(const f32x4*)f; pr1[p]=*(const f32x4*)(f+4); }
    else pr0[p]=*(const f32x4*)((const u16*)ins + aoff[p]);
  }
  #pragma unroll 1
  for (int ko=0; ko<1024; ko+=64){
    #pragma unroll
    for (int p=0;p<4;++p) gl_lds16(WiT + boff[p] + ko, &Bs[(p*32+wave*8)*64], lane);
    #pragma unroll
    for (int p=0;p<4;++p){
      uint4 w;
      if (isf){ w.x=pk2(pr0[p][0],pr0[p][1]); w.y=pk2(pr0[p][2],pr0[p][3]);
                w.z=pk2(pr1[p][0],pr1[p][1]); w.w=pk2(pr1[p][2],pr1[p][3]); }
      else { union{f32x4 f; uint4 u;} cv; cv.f=pr0[p]; w=cv.u; }
      *(uint4*)&As[(p*32+srow)*64 + swzc] = w;
    }
    __syncthreads();
    if (ko < 960){
      #pragma unroll
      for (int p=0;p<4;++p){
        if (isf){ const float* f=(const float*)ins + aoff[p] + ko + 64; pr0[p]=*(const f32x4*)f; pr1[p]=*(const f32x4*)(f+4); }
        else pr0[p]=*(const f32x4*)((const u16*)ins + aoff[p] + ko + 64);
      }
    }
    #pragma unroll
    for (int kk=0;kk<64;kk+=32){
      int rc = (kk + quad*8) ^ rsw;
      bf16x8 af[4], bfv[4];
      #pragma unroll
      for (int mi=0;mi<4;++mi) af[mi]  = *(const bf16x8*)&As[(wm*64+mi*16+l16)*64 + rc];
      #pragma unroll
      for (int ni=0;ni<4;++ni) bfv[ni] = *(const bf16x8*)&Bs[(wn*64+ni*16+l16)*64 + rc];
      #pragma unroll
      for (int mi=0;mi<4;++mi)
        #pragma unroll
        for (int ni=0;ni<4;++ni)
          acc[mi][ni] = __builtin_amdgcn_mfma_f32_16x16x32_bf16(af[mi],bfv[ni],acc[mi][ni],0,0,0);
    }
    __syncthreads();
  }
  #pragma unroll
  for (int mi=0;mi<4;++mi){
    int row = tm*128 + wm*64 + mi*16 + quad*4;
    #pragma unroll
    for (int ni=0;ni<4;++ni){
      int colB = tn*128 + wn*64 + ni*16 + l16;
      u16* op = xp + (size_t)row*3072 + colB;
      #pragma unroll
      for (int j=0;j<4;++j)
        op[(size_t)j*3072] = f2b(acc[mi][ni][j]);
    }
  }
}

// Pipelined + swizzled K=1024 panel for fat tiles (4 A rows / 3 B rows per thread).
#define FAT_PANEL(BASEARR, OFFARR, WT, NGRP)                                   \
    {                                                                          \
      f32x4 pr0[4], pr1[4];                                                    \
      _Pragma("unroll")                                                        \
      for (int p=0;p<4;++p){                                                   \
        if (isf){ const float* f=(const float*)BASEARR[p]+OFFARR[p];           \
          pr0[p]=*(const f32x4*)f; pr1[p]=*(const f32x4*)(f+4); }              \
        else pr0[p]=*(const f32x4*)((const u16*)BASEARR[p]+OFFARR[p]);         \
      }                                                                        \
      _Pragma("unroll 1")                                                      \
      for (int ko=0; ko<1024; ko+=64){                                         \
        _Pragma("unroll")                                                      \
        for (int p=0;p<3;++p)                                                  \
          gl_lds16(WT + boff[p] + ko, &Bs[(p*32+wave*8)*64], lane);            \
        _Pragma("unroll")                                                      \
        for (int p=0;p<4;++p){                                                 \
          uint4 w;                                                             \
          if (isf){ w.x=pk2(pr0[p][0],pr0[p][1]); w.y=pk2(pr0[p][2],pr0[p][3]);\
                    w.z=pk2(pr1[p][0],pr1[p][1]); w.w=pk2(pr1[p][2],pr1[p][3]);}\
          else { union{f32x4 f; uint4 u;} cv; cv.f=pr0[p]; w=cv.u; }           \
          *(uint4*)&As[(p*32+srow)*64 + swzc] = w;                             \
        }                                                                      \
        __syncthreads();                                                       \
        if (ko < 960){                                                         \
          _Pragma("unroll")                                                    \
          for (int p=0;p<4;++p){                                               \
            if (isf){ const float* f=(const float*)BASEARR[p]+OFFARR[p]+ko+64; \
              pr0[p]=*(const f32x4*)f; pr1[p]=*(const f32x4*)(f+4); }          \
            else pr0[p]=*(const f32x4*)((const u16*)BASEARR[p]+OFFARR[p]+ko+64);\
          }                                                                    \
        }                                                                      \
        _Pragma("unroll")                                                      \
        for (int kk=0;kk<64;kk+=32){                                           \
          int rc = (kk + quad*8) ^ rsw;                                        \
          bf16x8 af[4];                                                        \
          _Pragma("unroll")                                                    \
          for (int mi=0;mi<4;++mi)                                             \
            af[mi] = *(const bf16x8*)&As[(wm*64+mi*16+l16)*64 + rc];           \
          _Pragma("unroll")                                                    \
          for (int g=0;g<3;++g){                                               \
            bf16x8 bfr = *(const bf16x8*)&Bs[(g*32+wn*16+l16)*64 + rc];        \
            int grp = (g==2) ? (NGRP) : g;                                     \
            _Pragma("unroll")                                                  \
            for (int mi=0;mi<4;++mi)                                           \
              acc[mi][grp] = __builtin_amdgcn_mfma_f32_16x16x32_bf16(af[mi],bfr,acc[mi][grp],0,0,0); \
          }                                                                    \
        }                                                                      \
        __syncthreads();                                                       \
      }                                                                        \
    }

// Fat phase: 128 rows x 32 d-cols (96 gate cols).
template<bool HOIST>
__global__ __launch_bounds__(256, 3) void phase_fat(
    int s, const int* __restrict__ pcnt, const int* __restrict__ pbase,
    const int* __restrict__ row_tb, const int* __restrict__ row_src,
    const void* __restrict__ ins, const void* __restrict__ hiddens,
    const void* __restrict__ initc, const u16* __restrict__ WiT,
    const u16* __restrict__ WhT, const u16* __restrict__ bi_b,
    const u16* __restrict__ bhn_b, const int* __restrict__ dflag,
    const u16* __restrict__ xp, void* __restrict__ outv)
{
  int count = pcnt[s];
  if (count <= 0) return;
  int isf = dflag[3];
  int base = pbase[s];
  int mtiles = (count + 127) >> 7;
  int ntot = mtiles << 5;
  __shared__ u16 As[128*64];
  __shared__ u16 Bs[96*64];
  int tid=threadIdx.x, wave=tid>>6, lane=tid&63, quad=lane>>4, l16=lane&15;
  int wm=wave&1, wn=wave>>1;
  int srow = wave*8 + (lane>>3), c8=(lane&7)*8;
  int swzc = c8 ^ ((srow&7)<<3);
  int rsw = (l16&7)<<3;
  constexpr int NG = HOIST ? 3 : 4;

  for (int tile = blockIdx.x; tile < ntot; tile += gridDim.x){
    int tm = tile >> 5, dblk = tile & 31, d0 = dblk*32;
    unsigned xoff[4], hoff[4];
    const void* hbv[4];
    const void* xbv[4];
    #pragma unroll
    for (int p=0;p<4;++p){
      int lr = tm*128 + p*32 + srow;
      int idx = base + ((lr < count) ? lr : 0);
      int tb = row_tb[idx], code = row_src[idx];
      xoff[p] = (unsigned)tb*DIM + c8;
      xbv[p] = ins;
      size_t ho; const void* hb;
      hsrc(code, outv, hiddens, initc, &hb, &ho);
      hbv[p] = hb; hoff[p] = (unsigned)ho + c8;
    }
    int boff[3];
    #pragma unroll
    for (int p=0;p<3;++p) boff[p] = (p*DIM + d0 + srow)*DIM + swzc;
    f32x4 acc[4][NG] = {};

    if constexpr (!HOIST){
      FAT_PANEL(xbv, xoff, WiT, 2)
    }
    FAT_PANEL(hbv, hoff, WhT, (NG-1))

    // ---- fused GRU epilogue ----
    int col = d0 + wn*16 + l16;
    float br = b2f(bi_b[col]), bz = b2f(bi_b[1024+col]);
    float bn = b2f(bi_b[2048+col]), bh = b2f(bhn_b[col]);
    #pragma unroll
    for (int mi=0;mi<4;++mi){
      int lrow0 = tm*128 + wm*64 + mi*16 + quad*4;
      #pragma unroll
      for (int j=0;j<4;++j){
        int lrow = lrow0 + j;
        if (lrow >= count) continue;
        int idx = base + lrow;
        int tb = row_tb[idx], code = row_src[idx];
        size_t ho; const void* hb;
        hsrc(code, outv, hiddens, initc, &hb, &ho);
        float hpv = isf ? ((const float*)hb)[ho + col] : b2f(((const u16*)hb)[ho + col]);
        float xr = 0.f, xz = 0.f, xn = 0.f;
        if constexpr (HOIST){
          const u16* xrow = xp + (size_t)tb*3072 + col;
          xr = b2f(xrow[0]); xz = b2f(xrow[1024]); xn = b2f(xrow[2048]);
        }
        float r = sigf(br + xr + acc[mi][0][j]);
        float z = sigf(bz + xz + acc[mi][1][j]);
        float nx = HOIST ? xn : acc[mi][2][j];
        float n = tanh_f(bn + nx + r*(acc[mi][NG-1][j] + bh));
        float hnew = (1.0f - z)*n + z*hpv;
        size_t yo = (size_t)NB*DIM + (size_t)tb*DIM + col;
        if (isf) ((float*)outv)[yo] = hnew;
        else     ((u16*)outv)[yo] = f2b(hnew);
      }
    }
  }
}

// Pipelined + swizzled K=1024 panel for thin tiles (2 A rows per thread).
#define THIN_PANEL(BASEARR, OFFARR, WT, NGRP)                                  \
    {                                                                          \
      f32x4 pr0[2], pr1[2];                                                    \
      _Pragma("unroll")                                                        \
      for (int p=0;p<2;++p){                                                   \
        if (isf){ const float* f=(const float*)BASEARR[p]+OFFARR[p];           \
          pr0[p]=*(const f32x4*)f; pr1[p]=*(const f32x4*)(f+4); }              \
        else pr0[p]=*(const f32x4*)((const u16*)BASEARR[p]+OFFARR[p]);         \
      }                                                                        \
      _Pragma("unroll 1")                                                      \
      for (int ko=0; ko<1024; ko+=64){                                         \
        gl_lds16(WT + boffA + ko, &Bs[(wave*8)*64], lane);                     \
        if (wave < 2) gl_lds16(WT + boffB + ko, &Bs[(32+wave*8)*64], lane);    \
        _Pragma("unroll")                                                      \
        for (int p=0;p<2;++p){                                                 \
          uint4 w;                                                             \
          if (isf){ w.x=pk2(pr0[p][0],pr0[p][1]); w.y=pk2(pr0[p][2],pr0[p][3]);\
                    w.z=pk2(pr1[p][0],pr1[p][1]); w.w=pk2(pr1[p][2],pr1[p][3]);}\
          else { union{f32x4 f; uint4 u;} cv; cv.f=pr0[p]; w=cv.u; }           \
          *(uint4*)&As[(p*32+srow)*64 + swzc] = w;                             \
        }                                                                      \
        __syncthreads();                                                       \
        if (ko < 960){                                                         \
          _Pragma("unroll")                                                    \
          for (int p=0;p<2;++p){                                               \
            if (isf){ const float* f=(const float*)BASEARR[p]+OFFARR[p]+ko+64; \
              pr0[p]=*(const f32x4*)f; pr1[p]=*(const f32x4*)(f+4); }          \
            else pr0[p]=*(const f32x4*)((const u16*)BASEARR[p]+OFFARR[p]+ko+64);\
          }                                                                    \
        }                                                                      \
        _Pragma("unroll")                                                      \
        for (int kk=0;kk<64;kk+=32){                                           \
          int rc = (kk + quad*8) ^ rsw;                                        \
          bf16x8 af = *(const bf16x8*)&As[(wave*16+l16)*64 + rc];              \
          _Pragma("unroll")                                                    \
          for (int g=0;g<3;++g){                                               \
            bf16x8 bfr = *(const bf16x8*)&Bs[(g*16+l16)*64 + rc];              \
            int grp = (g==2) ? (NGRP) : g;                                     \
            acc[grp] = __builtin_amdgcn_mfma_f32_16x16x32_bf16(af,bfr,acc[grp],0,0,0); \
          }                                                                    \
        }                                                                      \
        __syncthreads();                                                       \
      }                                                                        \
    }

// Thin phase: 64 rows x 16 d-cols (48 gate cols).
template<bool HOIST>
__global__ __launch_bounds__(256, 4) void phase_thin(
    int s, const int* __restrict__ pcnt, const int* __restrict__ pbase,
    const int* __restrict__ row_tb, const int* __restrict__ row_src,
    const void* __restrict__ ins, const void* __restrict__ hiddens,
    const void* __restrict__ initc, const u16* __restrict__ WiT,
    const u16* __restrict__ WhT, const u16* __restrict__ bi_b,
    const u16* __restrict__ bhn_b, const int* __restrict__ dflag,
    const u16* __restrict__ xp, void* __restrict__ outv)
{
  int count = pcnt[s];
  if (count <= 0) return;
  int isf = dflag[3];
  int base = pbase[s];
  int mtiles = (count + 63) >> 6;
  int ntot = mtiles << 6;
  __shared__ u16 As[64*64];
  __shared__ u16 Bs[48*64];
  int tid=threadIdx.x, wave=tid>>6, lane=tid&63, quad=lane>>4, l16=lane&15;
  int srow = wave*8 + (lane>>3), c8=(lane&7)*8;
  int swzc = c8 ^ ((srow&7)<<3);
  int rsw = (l16&7)<<3;
  constexpr int NG = HOIST ? 3 : 4;

  for (int tile = blockIdx.x; tile < ntot; tile += gridDim.x){
    int tm = tile >> 6, dblk = tile & 63, d0 = dblk*16;
    unsigned xoff[2], hoff[2];
    const void* hbv[2];
    const void* xbv[2];
    #pragma unroll
    for (int p=0;p<2;++p){
      int lr = tm*64 + p*32 + srow;
      int idx = base + ((lr < count) ? lr : 0);
      int tb = row_tb[idx], code = row_src[idx];
      xoff[p] = (unsigned)tb*DIM + c8;
      xbv[p] = ins;
      size_t ho; const void* hb;
      hsrc(code, outv, hiddens, initc, &hb, &ho);
      hbv[p] = hb; hoff[p] = (unsigned)ho + c8;
    }
    int boffA = ((srow>>4)*DIM + d0 + (srow&15))*DIM + swzc;   // gates 0,1 (rows 0..31)
    int boffB = (2*DIM + d0 + srow)*DIM + swzc;                // gate 2 (rows 32..47, wave<2)
    f32x4 acc[NG] = {};

    if constexpr (!HOIST){
      THIN_PANEL(xbv, xoff, WiT, 2)
    }
    THIN_PANEL(hbv, hoff, WhT, (HOIST ? 2 : 3))

    int col = d0 + l16;
    float br = b2f(bi_b[col]), bz = b2f(bi_b[1024+col]);
    float bn = b2f(bi_b[2048+col]), bh = b2f(bhn_b[col]);
    int lrow0 = tm*64 + wave*16 + quad*4;
    #pragma unroll
    for (int j=0;j<4;++j){
      int lrow = lrow0 + j;
      if (lrow >= count) continue;
      int idx = base + lrow;
      int tb = row_tb[idx], code = row_src[idx];
      size_t ho; const void* hb;
      hsrc(code, outv, hiddens, initc, &hb, &ho);
      float hpv = isf ? ((const float*)hb)[ho + col] : b2f(((const u16*)hb)[ho + col]);
      float xr = 0.f, xz = 0.f, xn = 0.f;
      if constexpr (HOIST){
        const u16* xrow = xp + (size_t)tb*3072 + col;
        xr = b2f(xrow[0]); xz = b2f(xrow[1024]); xn = b2f(xrow[2048]);
      }
      float r = sigf(br + xr + acc[0][j]);
      float z = sigf(bz + xz + acc[1][j]);
      float nx = HOIST ? xn : acc[2][j];
      float n = tanh_f(bn + nx + r*(acc[NG-1][j] + bh));
      float hnew = (1.0f - z)*n + z*hpv;
      size_t yo = (size_t)NB*DIM + (size_t)tb*DIM + col;
      if (isf) ((float*)outv)[yo] = hnew;
      else     ((u16*)outv)[yo] = f2b(hnew);
    }
  }
}

__global__ void k_final(const int* dflag, void* out){
  int isf = dflag[3];
  size_t i = (size_t)(blockIdx.x*256 + threadIdx.x)*4;   // 64 blocks -> 65536
  size_t src = (size_t)NB*DIM + (size_t)(T_STEPS-1)*NB*DIM;
  if (isf){
    float* o = (float*)out;
    *(f32x4*)(o + i) = *(const f32x4*)(o + src + i);
  } else {
    u16* o = (u16*)out;
    *(uint2*)(o + i) = *(const uint2*)(o + src + i);
  }
}

extern "C" void kernel_launch(void* const* d_in, const int* in_sizes, int n_in,
                              void* d_out, int out_size, void* d_ws, size_t ws_size,
                              hipStream_t stream){
  const void* ins = d_in[0];
  const void* hid = d_in[1];
  const void* dn  = d_in[2];
  const void* ini = d_in[3];
  const void* Wi  = d_in[4];
  const void* Wh  = d_in[5];
  const void* bi  = d_in[6];
  const void* bhn = d_in[7];

  char* ws = (char*)d_ws;
  int* dflag  = (int*)(ws + 0);
  int* cnt    = (int*)(ws + 256);
  int* basep  = (int*)(ws + 512);
  int* cur    = (int*)(ws + 1024);
  int* s_of   = (int*)(ws + 4096);          // 64 KB
  int* row_tb = (int*)(ws + 69632);         // 64 KB
  int* row_src= (int*)(ws + 135168);        // 64 KB
  u16* bi_b   = (u16*)(ws + 200704);        // 6 KB
  u16* bhn_b  = (u16*)(ws + 208896);        // 2 KB
  u16* WiT    = (u16*)(ws + 262144);        // 6 MB
  u16* WhT    = (u16*)(ws + 6553600);       // 6 MB (end 12845056)
  u16* xp     = (u16*)(ws + 12845056);      // 96 MB bf16 Xp (if ws allows)

  // Hoisted-x path needs 12845056 + 16384*3072*2 = 113508352 bytes.
  const int hoist = (ws_size >= 113508352ull) ? 1 : 0;

  k_setup0<<<1,256,0,stream>>>(dn, ins, cnt, cur, dflag);
  k_assign<<<NB,T_STEPS,0,stream>>>(dn, dflag, s_of, cnt);
  k_scan<<<1,64,0,stream>>>(cnt, basep, cur);
  k_fill<<<NPH,256,0,stream>>>(dn, dflag, s_of, basep, row_tb, row_src);
  k_transpose<<<dim3(16,48),256,0,stream>>>(Wi, WiT, dflag);
  k_transpose<<<dim3(16,48),256,0,stream>>>(Wh, WhT, dflag);
  k_bias<<<16,256,0,stream>>>(bi, bhn, dflag, bi_b, bhn_b);

  if (hoist){
    k_xproj<<<3072,256,0,stream>>>(ins, WiT, dflag, xp);
    for (int s=0;s<6;++s)
      phase_fat<true><<<1024,256,0,stream>>>(s, cnt, basep, row_tb, row_src, ins, hid, ini,
                                             WiT, WhT, bi_b, bhn_b, dflag, xp, d_out);
    for (int s=6;s<NPH;++s)
      phase_thin<true><<<128,256,0,stream>>>(s, cnt, basep, row_tb, row_src, ins, hid, ini,
                                             WiT, WhT, bi_b, bhn_b, dflag, xp, d_out);
  } else {
    for (int s=0;s<6;++s)
      phase_fat<false><<<1024,256,0,stream>>>(s, cnt, basep, row_tb, row_src, ins, hid, ini,
                                              WiT, WhT, bi_b, bhn_b, dflag, xp, d_out);
    for (int s=6;s<NPH;++s)
      phase_thin<false><<<128,256,0,stream>>>(s, cnt, basep, row_tb, row_src, ins, hid, ini,
                                              WiT, WhT, bi_b, bhn_b, dflag, xp, d_out);
  }
  k_final<<<64,256,0,stream>>>(dflag, d_out);
}